// Round 8
// baseline (11137.377 us; speedup 1.0000x reference)
//
#include <hip/hip_runtime.h>

#define TT 512
#define II 64
#define HH 256
#define NG 16          // batch groups (16 rows each)
#define NS 8           // gate slices per group (32 channels each)

typedef _Float16 half8 __attribute__((ext_vector_type(8)));
typedef float f32x4 __attribute__((ext_vector_type(4)));

__device__ __forceinline__ float sigm(float x){ return 1.0f/(1.0f+__expf(-x)); }
__device__ __forceinline__ float tanhf_(float x){ float e=__expf(2.0f*x); return 1.0f-2.0f/(e+1.0f); }

union HU { _Float16 h; unsigned short u; };
__device__ __forceinline__ unsigned short h2u(float f){ HU x; x.h=(_Float16)f; return x.u; }

__device__ __forceinline__ half8 cvt8v(const float* __restrict__ p){
    f32x4 a = *(const f32x4*)p, b = *(const f32x4*)(p+4);
    half8 r;
    r[0]=(_Float16)a[0]; r[1]=(_Float16)a[1]; r[2]=(_Float16)a[2]; r[3]=(_Float16)a[3];
    r[4]=(_Float16)b[0]; r[5]=(_Float16)b[1]; r[6]=(_Float16)b[2]; r[7]=(_Float16)b[3];
    return r;
}

// Pin weight fragments into the AGPR file (opaque asm result cannot be
// rematerialized; AGPRs otherwise idle; MFMA reads A from AGPR directly).
__device__ __forceinline__ void pina(half8& v){ asm volatile("" : "+a"(v)); }
__device__ __forceinline__ void pinv(f32x4& v){ asm volatile("" : "+v"(v)); }

#define MFMA(A,B,C) __builtin_amdgcn_mfma_f32_16x16x32_f16((A),(B),(C),0,0,0)
#define ALOAD64(p)    __hip_atomic_load((p), __ATOMIC_RELAXED, __HIP_MEMORY_SCOPE_AGENT)
#define ASTORE64(p,v) __hip_atomic_store((p), (v), __ATOMIC_RELAXED, __HIP_MEMORY_SCOPE_AGENT)

#define TAGMSK 0xFFFF0000FFFF0000ULL
// payload merge: out u32 = {hi16 = payload of high u32, lo16 = payload of low u32}
__device__ __forceinline__ unsigned pk(unsigned long long v){
    return __builtin_amdgcn_perm((unsigned)(v>>32), (unsigned)v, 0x05040100u);
}

// Persistent gate-sliced, layer-pipelined 2-layer LSTM — tagged-data protocol.
// 128 WGs x 256 thr: group=blockIdx%16 (16 batch rows), slice=blockIdx/16.
// Each WAVE owns 8 channels (chanblock) of both layers. Every exchanged h value
// is a u32 {tag=t+1, f16 payload}: stores are fire-and-forget (no drain, no
// flag); consumers poll the data words themselves and validate tags. 2 MALL
// RTTs per superstep instead of 4.
// h tile layout: u32 [slot2][NG][row16][ch256].
__global__ __launch_bounds__(256,1) __attribute__((amdgpu_waves_per_eu(1)))
void lstm_pers(
    const float* __restrict__ x,
    const float* __restrict__ Wih0, const float* __restrict__ Whh0,
    const float* __restrict__ bih0, const float* __restrict__ bhh0,
    const float* __restrict__ Wih1, const float* __restrict__ Whh1,
    const float* __restrict__ bih1, const float* __restrict__ bhh1,
    const float* __restrict__ W1, const float* __restrict__ b1,
    const float* __restrict__ W2, const float* __restrict__ b2,
    unsigned* __restrict__ hb0, unsigned* __restrict__ hb1,
    float* __restrict__ out)
{
    // per-wave store-transpose tiles (wave-local; lgkmcnt only, no barrier)
    __shared__ __align__(16) unsigned twv[4][2][16][8];          // 4 KB
    __shared__ __align__(16) float epi[16*256 + 16*128];         // 24 KB (epilogue)

    const int tid = threadIdx.x;
    const int w   = tid >> 6;
    const int l   = tid & 63;
    const int lr  = l & 15;
    const int lk  = l >> 4;
    const int g   = blockIdx.x & (NG-1);
    const int s   = blockIdx.x >> 4;
    const int gbase = g * 16;
    const int cw  = s*32 + w*8;
    const int wid = s*4 + w;          // wave id in group == chanblock (0..31)

    // ---- resident weight fragments (MFMA A-operand), pinned into AGPRs ----
    half8 wA0[10][2];   // layer0: kt<8 -> Whh0 (K=256), kt=8,9 -> Wih0 (K=64)
    half8 wA1[16][2];   // layer1: kt<8 -> Whh1, kt>=8 -> Wih1
    f32x4 bias0v[2], bias1v[2];
#pragma unroll
    for (int m=0;m<2;++m){
        const int n = (lr&3)*HH + cw + m*4 + (lr>>2);
#pragma unroll
        for (int kt=0;kt<10;++kt){
            const float* src = (kt<8) ? (Whh0 + (size_t)n*HH + kt*32 + lk*8)
                                      : (Wih0 + (size_t)n*II + (kt-8)*32 + lk*8);
            wA0[kt][m] = cvt8v(src);
            pina(wA0[kt][m]);
        }
#pragma unroll
        for (int kt=0;kt<16;++kt){
            const float* src = (kt<8) ? (Whh1 + (size_t)n*HH + kt*32 + lk*8)
                                      : (Wih1 + (size_t)n*HH + (kt-8)*32 + lk*8);
            wA1[kt][m] = cvt8v(src);
            pina(wA1[kt][m]);
        }
        const int cD = cw + m*4 + lk;
#pragma unroll
        for (int j=0;j<4;++j){
            bias0v[m][j] = bih0[j*HH+cD] + bhh0[j*HH+cD];
            bias1v[m][j] = bih1[j*HH+cD] + bhh1[j*HH+cD];
        }
        pinv(bias0v[m]); pinv(bias1v[m]);
    }

    float c0s0=0.f, c0s1=0.f, c1s0=0.f, c1s1=0.f;

    // ---- x(0) register prefetch ----
    f32x4 xa, xb, xc, xd;
    {
        const float* xp = x + ((size_t)(gbase+lr)*TT)*II + lk*8;
        xa = *(const f32x4*)xp;      xb = *(const f32x4*)(xp+4);
        xc = *(const f32x4*)(xp+32); xd = *(const f32x4*)(xp+36);
    }

    half8 bh0[8] = {}, bh1[8] = {};   // current-step h fragments (B-operand)
    const int fo = lr*128 + lk*4;     // per-lane frag base (u64), + kt*16

    for (int t=0; t<=TT; ++t){
        f32x4 a0m0 = bias0v[0], a0m1 = bias0v[1];
        f32x4 a1m0 = bias1v[0], a1m1 = bias1v[1];

        // x-part of layer0 from prefetched registers
        if (t < TT){
            half8 bx0, bx1;
#pragma unroll
            for (int j=0;j<4;++j){
                bx0[j]   = (_Float16)xa[j];  bx0[4+j] = (_Float16)xb[j];
                bx1[j]   = (_Float16)xc[j];  bx1[4+j] = (_Float16)xd[j];
            }
            a0m0 = MFMA(wA0[8][0], bx0, a0m0);
            a0m1 = MFMA(wA0[8][1], bx0, a0m1);
            a0m0 = MFMA(wA0[9][0], bx1, a0m0);
            a0m1 = MFMA(wA0[9][1], bx1, a0m1);
        }

        if (t > 0){
            if (t < TT){
#pragma unroll
                for (int kt=0;kt<8;++kt){         // Whh0 * h0(t-1)
                    a0m0 = MFMA(wA0[kt][0], bh0[kt], a0m0);
                    a0m1 = MFMA(wA0[kt][1], bh0[kt], a0m1);
                }
            }
#pragma unroll
            for (int kt=0;kt<8;++kt){             // Wih1 * h0(t-1)
                a1m0 = MFMA(wA1[8+kt][0], bh0[kt], a1m0);
                a1m1 = MFMA(wA1[8+kt][1], bh0[kt], a1m1);
            }
            if (t >= 2){
#pragma unroll
                for (int kt=0;kt<8;++kt){         // Whh1 * h1(t-2)
                    a1m0 = MFMA(wA1[kt][0], bh1[kt], a1m0);
                    a1m1 = MFMA(wA1[kt][1], bh1[kt], a1m1);
                }
            }
        }

        // ---- activations -> wave-local LDS transpose tile (tagged u32) ----
        const unsigned tg = (unsigned)(t+1) << 16;
        if (t < TT){
            float ig=sigm(a0m0[0]), fg=sigm(a0m0[1]), gg=tanhf_(a0m0[2]), og=sigm(a0m0[3]);
            c0s0 = fg*c0s0 + ig*gg;
            twv[w][0][lr][lk]   = tg | h2u(og*tanhf_(c0s0));
            float ig1=sigm(a0m1[0]), fg1=sigm(a0m1[1]), gg1=tanhf_(a0m1[2]), og1=sigm(a0m1[3]);
            c0s1 = fg1*c0s1 + ig1*gg1;
            twv[w][0][lr][lk+4] = tg | h2u(og1*tanhf_(c0s1));
        }
        if (t > 0){
            float ig=sigm(a1m0[0]), fg=sigm(a1m0[1]), gg=tanhf_(a1m0[2]), og=sigm(a1m0[3]);
            c1s0 = fg*c1s0 + ig*gg;
            twv[w][1][lr][lk]   = tg | h2u(og*tanhf_(c1s0));
            float ig1=sigm(a1m1[0]), fg1=sigm(a1m1[1]), gg1=tanhf_(a1m1[2]), og1=sigm(a1m1[3]);
            c1s1 = fg1*c1s1 + ig1*gg1;
            twv[w][1][lr][lk+4] = tg | h2u(og1*tanhf_(c1s1));
        }
        asm volatile("s_waitcnt lgkmcnt(0)" ::: "memory");

        // x prefetch for t+1 (overlaps the stores below)
        if (t + 1 < TT){
            const float* xp = x + ((size_t)(gbase+lr)*TT + (t+1))*II + lk*8;
            xa = *(const f32x4*)xp;      xb = *(const f32x4*)(xp+4);
            xc = *(const f32x4*)(xp+32); xd = *(const f32x4*)(xp+36);
        }

        // ---- fire-and-forget tagged stores: lanes 0..31, 2 u64 per layer ----
        if (l < 32){
            const int row = l >> 1, half = l & 1;
            const size_t pidx = (size_t)row*128 + wid*4 + half*2;
            if (t < TT){
                const unsigned long long* sv =
                    (const unsigned long long*)&twv[w][0][row][half*4];
                unsigned long long* D0 = (unsigned long long*)hb0
                    + ((size_t)((t&1)*NG + g))*2048 + pidx;
                ASTORE64(D0,   sv[0]);
                ASTORE64(D0+1, sv[1]);
            }
            if (t > 0){
                const unsigned long long* sv =
                    (const unsigned long long*)&twv[w][1][row][half*4];
                unsigned long long* D1 = (unsigned long long*)hb1
                    + ((size_t)(((t-1)&1)*NG + g))*2048 + pidx;
                ASTORE64(D1,   sv[0]);
                ASTORE64(D1+1, sv[1]);
            }
        }

        // ---- poll the data itself: tags == t+1 on every consumed word ----
        if (t < TT){
            const unsigned long long pat =
                ((unsigned long long)(t+1)<<16) | ((unsigned long long)(t+1)<<48);
            const unsigned long long* T0 = (const unsigned long long*)hb0
                + ((size_t)((t&1)*NG + g))*2048;
            const unsigned long long* T1 = (const unsigned long long*)hb1
                + ((size_t)(((t+1)&1)*NG + g))*2048;
            const bool need1 = (t >= 1);
            for (;;){
                bool ok = true;
#pragma unroll
                for (int kt=0;kt<8;++kt){
                    const unsigned long long* p = T0 + fo + kt*16;
                    unsigned long long v0=ALOAD64(p),   v1=ALOAD64(p+1);
                    unsigned long long v2=ALOAD64(p+2), v3=ALOAD64(p+3);
                    ok = ok && ((v0&TAGMSK)==pat) && ((v1&TAGMSK)==pat)
                            && ((v2&TAGMSK)==pat) && ((v3&TAGMSK)==pat);
                    union{unsigned u[4]; half8 h;} cv;
                    cv.u[0]=pk(v0); cv.u[1]=pk(v1); cv.u[2]=pk(v2); cv.u[3]=pk(v3);
                    bh0[kt] = cv.h;
                }
                if (need1){
#pragma unroll
                    for (int kt=0;kt<8;++kt){
                        const unsigned long long* p = T1 + fo + kt*16;
                        unsigned long long v0=ALOAD64(p),   v1=ALOAD64(p+1);
                        unsigned long long v2=ALOAD64(p+2), v3=ALOAD64(p+3);
                        ok = ok && ((v0&TAGMSK)==pat) && ((v1&TAGMSK)==pat)
                                && ((v2&TAGMSK)==pat) && ((v3&TAGMSK)==pat);
                        union{unsigned u[4]; half8 h;} cv;
                        cv.u[0]=pk(v0); cv.u[1]=pk(v1); cv.u[2]=pk(v2); cv.u[3]=pk(v3);
                        bh1[kt] = cv.h;
                    }
                }
                if (__all((int)ok)) break;
            }
        }
    }

    // ---- epilogue: slice 0 of each group computes the MLP head ----
    if (s == 0){
        float* hl  = epi;              // [16][256]
        float* zsh = epi + 16*256;     // [16][128]
        const unsigned long long patE =
            ((unsigned long long)(TT+1)<<16) | ((unsigned long long)(TT+1)<<48);
        const unsigned long long* HL = (const unsigned long long*)hb1
            + ((size_t)(((TT-1)&1)*NG + g))*2048;
        for (int i = tid; i < 1024; i += 256){
            const int r = i >> 6, q = i & 63;
            const size_t idx = (size_t)r*128 + q*2;
            unsigned long long a, b;
            do { a = ALOAD64(HL + idx);     } while ((a & TAGMSK) != patE);
            do { b = ALOAD64(HL + idx + 1); } while ((b & TAGMSK) != patE);
            HU u0, u1, u2, u3;
            u0.u = (unsigned short)a; u1.u = (unsigned short)(a>>32);
            u2.u = (unsigned short)b; u3.u = (unsigned short)(b>>32);
            hl[r*256 + q*4 + 0] = (float)u0.h;
            hl[r*256 + q*4 + 1] = (float)u1.h;
            hl[r*256 + q*4 + 2] = (float)u2.h;
            hl[r*256 + q*4 + 3] = (float)u3.h;
        }
        __syncthreads();
        for (int idx = tid; idx < 2048; idx += 256){
            const int r = idx >> 7, j = idx & 127;
            const float* wrow = W1 + j*HH;
            const float* hr = hl + r*256;
            float ssum = b1[j];
            for (int k=0;k<HH;k+=4){
                f32x4 wv = *(const f32x4*)(wrow + k);
                ssum += hr[k]*wv[0] + hr[k+1]*wv[1] + hr[k+2]*wv[2] + hr[k+3]*wv[3];
            }
            zsh[r*128 + j] = tanhf_(ssum);
        }
        __syncthreads();
        for (int idx = tid; idx < 1536; idx += 256){
            const int r = idx / 96, o = idx - r*96;
            const float* wrow = W2 + o*128;
            const float* zr = zsh + r*128;
            float ssum = b2[o];
            for (int k=0;k<128;k+=4){
                f32x4 wv = *(const f32x4*)(wrow + k);
                ssum += zr[k]*wv[0] + zr[k+1]*wv[1] + zr[k+2]*wv[2] + zr[k+3]*wv[3];
            }
            out[(size_t)(gbase+r)*96 + o] = ssum;
        }
    }
}

extern "C" void kernel_launch(void* const* d_in, const int* in_sizes, int n_in,
                              void* d_out, int out_size, void* d_ws, size_t ws_size,
                              hipStream_t stream) {
    const float* x    = (const float*)d_in[0];
    const float* Wih0 = (const float*)d_in[1];
    const float* Whh0 = (const float*)d_in[2];
    const float* bih0 = (const float*)d_in[3];
    const float* bhh0 = (const float*)d_in[4];
    const float* Wih1 = (const float*)d_in[5];
    const float* Whh1 = (const float*)d_in[6];
    const float* bih1 = (const float*)d_in[7];
    const float* bhh1 = (const float*)d_in[8];
    const float* W1   = (const float*)d_in[9];
    const float* b1   = (const float*)d_in[10];
    const float* W2   = (const float*)d_in[11];
    const float* b2   = (const float*)d_in[12];

    // workspace: hb0 | hb1, each u32 [2][NG][16][256] = 512 KB; tags zeroed per call
    unsigned* hb0 = (unsigned*)d_ws;
    unsigned* hb1 = (unsigned*)((char*)d_ws + 524288);

    hipMemsetAsync(d_ws, 0, 1048576, stream);

    hipLaunchKernelGGL(lstm_pers, dim3(NG*NS), dim3(256), 0, stream,
                       x, Wih0, Whh0, bih0, bhh0,
                       Wih1, Whh1, bih1, bhh1,
                       W1, b1, W2, b2,
                       hb0, hb1, (float*)d_out);
}

// Round 9
// 2715.516 us; speedup vs baseline: 4.1014x; 4.1014x over previous
//
#include <hip/hip_runtime.h>

#define TT 512
#define II 64
#define HH 256
#define NG 16          // total batch groups (16 rows each)
#define NS 8           // gate slices (32 channels each)
#define FST 520        // flag lines per group (>= TT+1), 32 u16 (64B) each

typedef _Float16 half8 __attribute__((ext_vector_type(8)));
typedef float f32x4 __attribute__((ext_vector_type(4)));

__device__ __forceinline__ float sigm(float x){ return 1.0f/(1.0f+__expf(-x)); }
__device__ __forceinline__ float tanhf_(float x){ float e=__expf(2.0f*x); return 1.0f-2.0f/(e+1.0f); }

union HU { _Float16 h; unsigned short u; };
__device__ __forceinline__ unsigned short h2u(float f){ HU x; x.h=(_Float16)f; return x.u; }

__device__ __forceinline__ half8 cvt8v(const float* __restrict__ p){
    f32x4 a = *(const f32x4*)p, b = *(const f32x4*)(p+4);
    half8 r;
    r[0]=(_Float16)a[0]; r[1]=(_Float16)a[1]; r[2]=(_Float16)a[2]; r[3]=(_Float16)a[3];
    r[4]=(_Float16)b[0]; r[5]=(_Float16)b[1]; r[6]=(_Float16)b[2]; r[7]=(_Float16)b[3];
    return r;
}

// Pin weight fragments into the AGPR file (opaque asm result cannot be
// rematerialized; AGPRs otherwise idle; MFMA reads A from AGPR directly).
__device__ __forceinline__ void pina(half8& v){ asm volatile("" : "+a"(v)); }
__device__ __forceinline__ void pinv(f32x4& v){ asm volatile("" : "+v"(v)); }

#define MFMA(A,B,C) __builtin_amdgcn_mfma_f32_16x16x32_f16((A),(B),(C),0,0,0)
#define ALOAD64(p)    __hip_atomic_load((p), __ATOMIC_RELAXED, __HIP_MEMORY_SCOPE_AGENT)
#define ASTORE64(p,v) __hip_atomic_store((p), (v), __ATOMIC_RELAXED, __HIP_MEMORY_SCOPE_AGENT)
#define ASTORE16(p,v) __hip_atomic_store((p), (v), __ATOMIC_RELAXED, __HIP_MEMORY_SCOPE_AGENT)

// Poll one group's flag line (32 u16 slots) until all == t+1.
// First successful iteration implies s_waitcnt vmcnt(0) -> drains this wave's
// earlier stores (vmcnt completes in issue order) — used as the free drain.
__device__ __forceinline__ void pollflag(const unsigned short* fgrp, int t, int l){
    const unsigned long long pat = 0x0001000100010001ULL * (unsigned long long)(t+1);
    const unsigned long long* fp = (const unsigned long long*)(fgrp + (size_t)t*32);
    for (;;){
        unsigned long long v = (l < 8) ? ALOAD64(fp + l) : pat;
        if (__all(v == pat)) break;
    }
}

// Load this lane's 8 MFMA-B fragments (one layer) from a blocked h tile.
__device__ __forceinline__ void load8(const unsigned long long* __restrict__ T,
                                      const int fo, half8 (&bh)[8]){
#pragma unroll
    for (int kt=0;kt<8;++kt){
        const unsigned long long* p = T + fo + kt*128;
        unsigned long long a = ALOAD64(p), b = ALOAD64(p+1);
        union { unsigned long long u[2]; half8 h; } cv;
        cv.u[0]=a; cv.u[1]=b;
        bh[kt] = cv.h;
    }
}

// One group-step: compute h0(t) [t<TT] and h1(t-1) [t>0], act, fire stores.
__device__ __forceinline__ void gstep(
    const int t, const int lr, const int lk, const int wid, const int g, const int l,
    const half8 (&wA0)[10][2], const half8 (&wA1)[16][2],
    const f32x4 (&b0v)[2], const f32x4 (&b1v)[2],
    half8 (&bh0)[8], half8 (&bh1)[8],
    const f32x4& xa, const f32x4& xb, const f32x4& xc, const f32x4& xd,
    float& c0a, float& c0b, float& c1a, float& c1b,
    unsigned short (&twl)[2][16][8],
    unsigned long long* __restrict__ hb0u, unsigned long long* __restrict__ hb1u)
{
    f32x4 a0m0 = b0v[0], a0m1 = b0v[1];
    f32x4 a1m0 = b1v[0], a1m1 = b1v[1];

    if (t < TT){
        half8 bx0, bx1;
#pragma unroll
        for (int j=0;j<4;++j){
            bx0[j]   = (_Float16)xa[j];  bx0[4+j] = (_Float16)xb[j];
            bx1[j]   = (_Float16)xc[j];  bx1[4+j] = (_Float16)xd[j];
        }
        a0m0 = MFMA(wA0[8][0], bx0, a0m0);
        a0m1 = MFMA(wA0[8][1], bx0, a0m1);
        a0m0 = MFMA(wA0[9][0], bx1, a0m0);
        a0m1 = MFMA(wA0[9][1], bx1, a0m1);
    }
    if (t > 0){
        if (t < TT){
#pragma unroll
            for (int kt=0;kt<8;++kt){             // Whh0 * h0(t-1)
                a0m0 = MFMA(wA0[kt][0], bh0[kt], a0m0);
                a0m1 = MFMA(wA0[kt][1], bh0[kt], a0m1);
            }
        }
#pragma unroll
        for (int kt=0;kt<8;++kt){                 // Wih1 * h0(t-1)
            a1m0 = MFMA(wA1[8+kt][0], bh0[kt], a1m0);
            a1m1 = MFMA(wA1[8+kt][1], bh0[kt], a1m1);
        }
        if (t >= 2){
#pragma unroll
            for (int kt=0;kt<8;++kt){             // Whh1 * h1(t-2)
                a1m0 = MFMA(wA1[kt][0], bh1[kt], a1m0);
                a1m1 = MFMA(wA1[kt][1], bh1[kt], a1m1);
            }
        }
    }

    if (t < TT){
        float ig=sigm(a0m0[0]), fg=sigm(a0m0[1]), gg=tanhf_(a0m0[2]), og=sigm(a0m0[3]);
        c0a = fg*c0a + ig*gg;
        twl[0][lr][lk]   = h2u(og*tanhf_(c0a));
        float ig1=sigm(a0m1[0]), fg1=sigm(a0m1[1]), gg1=tanhf_(a0m1[2]), og1=sigm(a0m1[3]);
        c0b = fg1*c0b + ig1*gg1;
        twl[0][lr][lk+4] = h2u(og1*tanhf_(c0b));
    }
    if (t > 0){
        float ig=sigm(a1m0[0]), fg=sigm(a1m0[1]), gg=tanhf_(a1m0[2]), og=sigm(a1m0[3]);
        c1a = fg*c1a + ig*gg;
        twl[1][lr][lk]   = h2u(og*tanhf_(c1a));
        float ig1=sigm(a1m1[0]), fg1=sigm(a1m1[1]), gg1=tanhf_(a1m1[2]), og1=sigm(a1m1[3]);
        c1b = fg1*c1b + ig1*gg1;
        twl[1][lr][lk+4] = h2u(og1*tanhf_(c1b));
    }
    asm volatile("s_waitcnt lgkmcnt(0)" ::: "memory");

    // coalesced blocked piece stores: lanes 0..31, one u64 each, 256B/wave
    if (l < 32){
        const int row = l >> 1, hf = l & 1;
        if (t < TT){
            unsigned long long v = *(const unsigned long long*)&twl[0][row][hf*4];
            ASTORE64(hb0u + ((size_t)((t&1)*NG + g))*1024 + wid*32 + l, v);
        }
        if (t > 0){
            unsigned long long v = *(const unsigned long long*)&twl[1][row][hf*4];
            ASTORE64(hb1u + ((size_t)(((t-1)&1)*NG + g))*1024 + wid*32 + l, v);
        }
    }
}

__device__ __forceinline__ void ldx(const float* __restrict__ x, int grow, int t, int lk,
                                    f32x4& a, f32x4& b, f32x4& c, f32x4& d){
    const float* xp = x + ((size_t)grow*TT + t)*II + lk*8;
    a = *(const f32x4*)xp;      b = *(const f32x4*)(xp+4);
    c = *(const f32x4*)(xp+32); d = *(const f32x4*)(xp+36);
}

// Persistent gate-sliced 2-layer LSTM, TWO batch groups per WG (A/B interleave).
// 64 WGs x 256 thr: gpair=blockIdx&7 (groups 2gp, 2gp+1), slice=blockIdx>>3.
// MALL RTTs of each group's {drain, flag, load} overlap the other group's work.
__global__ __launch_bounds__(256,1) __attribute__((amdgpu_waves_per_eu(1)))
void lstm_pers(
    const float* __restrict__ x,
    const float* __restrict__ Wih0, const float* __restrict__ Whh0,
    const float* __restrict__ bih0, const float* __restrict__ bhh0,
    const float* __restrict__ Wih1, const float* __restrict__ Whh1,
    const float* __restrict__ bih1, const float* __restrict__ bhh1,
    const float* __restrict__ W1, const float* __restrict__ b1,
    const float* __restrict__ W2, const float* __restrict__ b2,
    unsigned short* __restrict__ flags,
    _Float16* __restrict__ hb0, _Float16* __restrict__ hb1,
    float* __restrict__ out)
{
    __shared__ __align__(16) unsigned short twv[4][2][16][8];   // 2 KB
    __shared__ __align__(16) float epi[16*256 + 16*128];        // 24 KB (epilogue)

    const int tid = threadIdx.x;
    const int w   = tid >> 6;
    const int l   = tid & 63;
    const int lr  = l & 15;
    const int lk  = l >> 4;
    const int gp  = blockIdx.x & 7;
    const int s   = blockIdx.x >> 3;
    const int gA  = gp*2, gB = gp*2 + 1;
    const int cw  = s*32 + w*8;
    const int wid = s*4 + w;          // wave id in group == chanblock (0..31)

    unsigned long long* hb0u = (unsigned long long*)hb0;
    unsigned long long* hb1u = (unsigned long long*)hb1;

    // ---- resident weight fragments (MFMA A-operand), pinned into AGPRs ----
    half8 wA0[10][2];   // layer0: kt<8 -> Whh0 (K=256), kt=8,9 -> Wih0 (K=64)
    half8 wA1[16][2];   // layer1: kt<8 -> Whh1, kt>=8 -> Wih1
    f32x4 bias0v[2], bias1v[2];
#pragma unroll
    for (int m=0;m<2;++m){
        const int n = (lr&3)*HH + cw + m*4 + (lr>>2);
#pragma unroll
        for (int kt=0;kt<10;++kt){
            const float* src = (kt<8) ? (Whh0 + (size_t)n*HH + kt*32 + lk*8)
                                      : (Wih0 + (size_t)n*II + (kt-8)*32 + lk*8);
            wA0[kt][m] = cvt8v(src);
            pina(wA0[kt][m]);
        }
#pragma unroll
        for (int kt=0;kt<16;++kt){
            const float* src = (kt<8) ? (Whh1 + (size_t)n*HH + kt*32 + lk*8)
                                      : (Wih1 + (size_t)n*HH + (kt-8)*32 + lk*8);
            wA1[kt][m] = cvt8v(src);
            pina(wA1[kt][m]);
        }
        const int cD = cw + m*4 + lk;
#pragma unroll
        for (int j=0;j<4;++j){
            bias0v[m][j] = bih0[j*HH+cD] + bhh0[j*HH+cD];
            bias1v[m][j] = bih1[j*HH+cD] + bhh1[j*HH+cD];
        }
        pinv(bias0v[m]); pinv(bias1v[m]);
    }

    float cA0a=0.f, cA0b=0.f, cA1a=0.f, cA1b=0.f;
    float cB0a=0.f, cB0b=0.f, cB1a=0.f, cB1b=0.f;
    unsigned short* fgrpA = flags + (size_t)gA*FST*32;
    unsigned short* fgrpB = flags + (size_t)gB*FST*32;
    const int fo = lk*32 + lr*2;      // per-lane frag base (u64), + kt*128

    // ---- x(0) register prefetch for both groups ----
    f32x4 xAa,xAb,xAc,xAd, xBa,xBb,xBc,xBd;
    ldx(x, gA*16 + lr, 0, lk, xAa,xAb,xAc,xAd);
    ldx(x, gB*16 + lr, 0, lk, xBa,xBb,xBc,xBd);

    half8 bhA0[8] = {}, bhA1[8] = {};
    half8 bhB0[8] = {}, bhB1[8] = {};

    for (int t=0; t<=TT; ++t){
        // ===== A phase: compute/act/store group A step t =====
        gstep(t, lr, lk, wid, gA, l, wA0, wA1, bias0v, bias1v,
              bhA0, bhA1, xAa,xAb,xAc,xAd, cA0a,cA0b,cA1a,cA1b,
              twv[w], hb0u, hb1u);
        if (t + 1 < TT) ldx(x, gA*16 + lr, t+1, lk, xAa,xAb,xAc,xAd);

        // ===== poll B(t-1) — implicit vmcnt(0) drains A's stores =====
        if (t > 0) pollflag(fgrpB, t-1, l);
        else       asm volatile("s_waitcnt vmcnt(0)" ::: "memory");
        if (l == 0) ASTORE16(&fgrpA[(size_t)t*32 + wid], (unsigned short)(t+1));

        // ===== load B fragments (data t-1) =====
        if (t >= 1){
            load8(hb0u + ((size_t)(((t-1)&1)*NG + gB))*1024, fo, bhB0);
            if (t >= 2)
                load8(hb1u + ((size_t)((t&1)*NG + gB))*1024, fo, bhB1);
        }

        // ===== B phase: compute/act/store group B step t =====
        gstep(t, lr, lk, wid, gB, l, wA0, wA1, bias0v, bias1v,
              bhB0, bhB1, xBa,xBb,xBc,xBd, cB0a,cB0b,cB1a,cB1b,
              twv[w], hb0u, hb1u);
        if (t + 1 < TT) ldx(x, gB*16 + lr, t+1, lk, xBa,xBb,xBc,xBd);

        // ===== poll A(t) — implicit vmcnt(0) drains B's stores =====
        pollflag(fgrpA, t, l);
        if (l == 0) ASTORE16(&fgrpB[(size_t)t*32 + wid], (unsigned short)(t+1));

        // ===== load A fragments (data t) for next iteration =====
        if (t < TT){
            load8(hb0u + ((size_t)((t&1)*NG + gA))*1024, fo, bhA0);
            if (t >= 1)
                load8(hb1u + ((size_t)(((t+1)&1)*NG + gA))*1024, fo, bhA1);
        }
    }

    // ---- epilogue: slice-0 WGs compute the MLP head for both groups ----
    if (s == 0){
        pollflag(fgrpB, TT, l);   // A(TT) confirmed in-loop; confirm B(TT)
        float* hl  = epi;              // [16][256]
        float* zsh = epi + 16*256;     // [16][128]
#pragma unroll 1
        for (int gi=0; gi<2; ++gi){
            const int gg = gA + gi;
            const int gbase = gg*16;
            const unsigned long long* HL = hb1u
                + ((size_t)(((TT-1)&1)*NG + gg))*1024;
            for (int i = tid; i < 1024; i += 256){
                const int r = i >> 6, q = i & 63;
                const size_t gix = (size_t)(q>>1)*32 + r*2 + (q&1);
                unsigned long long v = ALOAD64(HL + gix);
                union { unsigned long long u; _Float16 h[4]; } cv; cv.u = v;
#pragma unroll
                for (int e=0;e<4;++e) hl[r*256 + q*4 + e] = (float)cv.h[e];
            }
            __syncthreads();
            for (int idx = tid; idx < 2048; idx += 256){
                const int r = idx >> 7, j = idx & 127;
                const float* wrow = W1 + j*HH;
                const float* hr = hl + r*256;
                float ssum = b1[j];
                for (int k=0;k<HH;k+=4){
                    f32x4 wv = *(const f32x4*)(wrow + k);
                    ssum += hr[k]*wv[0] + hr[k+1]*wv[1] + hr[k+2]*wv[2] + hr[k+3]*wv[3];
                }
                zsh[r*128 + j] = tanhf_(ssum);
            }
            __syncthreads();
            for (int idx = tid; idx < 1536; idx += 256){
                const int r = idx / 96, o = idx - r*96;
                const float* wrow = W2 + o*128;
                const float* zr = zsh + r*128;
                float ssum = b2[o];
                for (int k=0;k<128;k+=4){
                    f32x4 wv = *(const f32x4*)(wrow + k);
                    ssum += zr[k]*wv[0] + zr[k+1]*wv[1] + zr[k+2]*wv[2] + zr[k+3]*wv[3];
                }
                out[(size_t)(gbase+r)*96 + o] = ssum;
            }
            __syncthreads();
        }
    }
}

extern "C" void kernel_launch(void* const* d_in, const int* in_sizes, int n_in,
                              void* d_out, int out_size, void* d_ws, size_t ws_size,
                              hipStream_t stream) {
    const float* x    = (const float*)d_in[0];
    const float* Wih0 = (const float*)d_in[1];
    const float* Whh0 = (const float*)d_in[2];
    const float* bih0 = (const float*)d_in[3];
    const float* bhh0 = (const float*)d_in[4];
    const float* Wih1 = (const float*)d_in[5];
    const float* Whh1 = (const float*)d_in[6];
    const float* bih1 = (const float*)d_in[7];
    const float* bhh1 = (const float*)d_in[8];
    const float* W1   = (const float*)d_in[9];
    const float* b1   = (const float*)d_in[10];
    const float* W2   = (const float*)d_in[11];
    const float* b2   = (const float*)d_in[12];

    // workspace: flags 16*520*64 B = 532,480 (zeroed per call)
    //            hb0/hb1 blocked: 2 bufs * 16 g * 32 blk * 256 B = 262,144 B each
    unsigned short* flags = (unsigned short*)d_ws;
    _Float16* hb0 = (_Float16*)((char*)d_ws + 532480);
    _Float16* hb1 = (_Float16*)((char*)d_ws + 532480 + 262144);

    hipMemsetAsync(d_ws, 0, 532480, stream);

    hipLaunchKernelGGL(lstm_pers, dim3(64), dim3(256), 0, stream,
                       x, Wih0, Whh0, bih0, bhh0,
                       Wih1, Whh1, bih1, bhh1,
                       W1, b1, W2, b2,
                       flags, hb0, hb1, (float*)d_out);
}